// Round 8
// baseline (179.244 us; speedup 1.0000x reference)
//
#include <hip/hip_runtime.h>

#define BSZ   32
#define SEQ   64
#define HID   256
#define G4    1024
#define NSTEP 64
#define QB    8      // blocks per batch
#define JB    32     // hidden units per block

typedef unsigned long long u64;
typedef unsigned int       u32;
typedef _Float16 h2v __attribute__((ext_vector_type(2)));

__device__ __forceinline__ u32 pk2(float lo, float hi) {
  return __builtin_bit_cast(u32, __builtin_amdgcn_cvt_pkrtz(lo, hi));
}
__device__ __forceinline__ float dot2_(u32 w, u32 h, float acc) {
#if __has_builtin(__builtin_amdgcn_fdot2)
  return __builtin_amdgcn_fdot2(__builtin_bit_cast(h2v, w),
                                __builtin_bit_cast(h2v, h), acc, false);
#else
  const h2v wv = __builtin_bit_cast(h2v, w), hv = __builtin_bit_cast(h2v, h);
  return acc + (float)wv[0] * (float)hv[0] + (float)wv[1] * (float)hv[1];
#endif
}
__device__ __forceinline__ float sigmoid_f(float x) {
  return __fdividef(1.f, 1.f + __expf(-x));
}
__device__ __forceinline__ float tanh_f(float x) {
  const float xc = fminf(fmaxf(x, -18.f), 18.f);   // c reaches ±63; tanh(18)=1.0f
  const float e  = __expf(2.f * xc);
  return __fdividef(e - 1.f, e + 1.f);
}

// ---------------------------------------------------------------------------
// R8 = R6 structure (8-way split, 1 block/CU, XCD-swizzled) + fp16 W tiles.
// grid = 256 = 32 b x 8 q, b = idx&31, q = idx>>5 => XCD = b%8: all 8
// siblings of a batch share one XCD's L2 for the tagged h exchange.
//
// W tiles (Wh, then-reused-slot Wi) live in LDS as fp16 k-pair half2:
//   lds_w[kp*128 + col] (u32) = {lo=W[2kp][col], hi=W[2kp+1][col]}, col=g*32+jj
// MAC per thread: 16 W-b128 + 4 h-b128 + 64 v_dot2_f32_f16 (fp32 accum).
// (R6 was 40 b128 fp32 — the MAC LDS stream was the largest step-wall term.)
//
// h exchange: 128 tagged words per batch: {hi32 = half2(h_2i,h_2i+1) | lo32 =
// step tag}, relaxed agent-scope atomics, parity double-buffer. Thread polls
// word tid>>1 (pairs redundant), stages hs2[tid>>1]; reader kq=tid>>5 reads
// hs2[kq*16..+15] staged by tids kq*32..+31 = its own half-wave => no
// post-stage barrier (R6-proven). One barrier/step. 0xAA poison != tags 1..64.
// ---------------------------------------------------------------------------
__global__ __launch_bounds__(256, 1) void k_fused(
    const float* __restrict__ x, const float* __restrict__ Wa,
    const float* __restrict__ Wi, const float* __restrict__ Wh,
    const float* __restrict__ bias, const float* __restrict__ Wf,
    const float* __restrict__ bf,
    u64* __restrict__ tht2, u64* __restrict__ ctxT, float* __restrict__ out)
{
  const int b    = blockIdx.x & 31;   // siblings of a batch share an XCD
  const int q    = blockIdx.x >> 5;
  const int tid  = threadIdx.x;
  const int lane = tid & 63;
  const int wv   = tid >> 6;
  const int jq   = tid & 7;           // hidden quad (j = jq*4 .. +3)
  const int g    = (tid >> 3) & 3;    // gate
  const int kq   = tid >> 5;          // k-slice (0..7), half-wave granular
  const int cq4  = g * 8 + jq;        // col-quad index (0..31)

  __shared__ __align__(16) u32   smem[26944];       // phase A floats / W16 tile
  __shared__ __align__(16) u32   hs2[128];          // staged h (half2 words)
  __shared__ __align__(16) float cs[256];           // staged ctx (fp32)
  __shared__ __align__(16) float gred[2][8][128];   // [par][kq][g*32+j]
  __shared__ float red[4];
  float* arena = (float*)smem;
  u32*   lds_w = smem;

  const float* xb = x + (size_t)b * SEQ * HID;

  // =================== phase A: context slice (verified R4..R7) =============
  // arena: xs[64][260] @0 ; was[256][32] @16640 ; Ls[64][33] @24832
#pragma unroll
  for (int it = 0; it < 16; ++it) {
    const int gl = it * 1024 + tid * 4;
    const int s = gl >> 8, k = gl & 255;
    *(float4*)&arena[s * 260 + k] = *(const float4*)(xb + gl);
  }
#pragma unroll
  for (int it = 0; it < 8; ++it) {
    const int idx = it * 256 + tid;
    const int k = idx >> 3, cq = idx & 7;
    *(float4*)&arena[16640 + k * 32 + cq * 4] =
        *(const float4*)(Wa + (size_t)k * HID + q * JB + cq * 4);
  }
  __syncthreads();

  {  // logits L[s][jl] = sum_k x[s][k] * Wa[k][q*32+jl]
    const int ts = tid >> 2, tc = tid & 3;
    float l0 = 0.f, l1 = 0.f, l2 = 0.f, l3 = 0.f,
          l4 = 0.f, l5 = 0.f, l6 = 0.f, l7 = 0.f;
    const float* xrow = &arena[ts * 260];
    const float* wab  = &arena[16640 + tc * 8];
    for (int k4 = 0; k4 < 64; ++k4) {
      const float4 xv = *(const float4*)&xrow[k4 * 4];
#define LSTEP(XE, KO)                                                        \
      { const float4 wa = *(const float4*)&wab[(k4 * 4 + KO) * 32];          \
        const float4 wb2 = *(const float4*)&wab[(k4 * 4 + KO) * 32 + 4];     \
        l0 += (XE) * wa.x;  l1 += (XE) * wa.y;  l2 += (XE) * wa.z;           \
        l3 += (XE) * wa.w;  l4 += (XE) * wb2.x; l5 += (XE) * wb2.y;          \
        l6 += (XE) * wb2.z; l7 += (XE) * wb2.w; }
      LSTEP(xv.x, 0) LSTEP(xv.y, 1) LSTEP(xv.z, 2) LSTEP(xv.w, 3)
#undef LSTEP
    }
    float* lrow = &arena[24832 + ts * 33 + tc * 8];
    lrow[0] = l0; lrow[1] = l1; lrow[2] = l2; lrow[3] = l3;
    lrow[4] = l4; lrow[5] = l5; lrow[6] = l6; lrow[7] = l7;
  }
  __syncthreads();

  {  // softmax over s (shift-invariance: ht/ct/ba cancel) + ctx publish
    const int jx = tid >> 3, sp = tid & 7;
    float lg[8];
#pragma unroll
    for (int e = 0; e < 8; ++e) lg[e] = arena[24832 + (sp * 8 + e) * 33 + jx];
    float m = lg[0];
#pragma unroll
    for (int e = 1; e < 8; ++e) m = fmaxf(m, lg[e]);
    m = fmaxf(m, __shfl_xor(m, 1));
    m = fmaxf(m, __shfl_xor(m, 2));
    m = fmaxf(m, __shfl_xor(m, 4));
    float ex[8], sm = 0.f;
#pragma unroll
    for (int e = 0; e < 8; ++e) { ex[e] = __expf(lg[e] - m); sm += ex[e]; }
    sm += __shfl_xor(sm, 1);
    sm += __shfl_xor(sm, 2);
    sm += __shfl_xor(sm, 4);
    const float inv = 1.f / sm;
    const int gj = q * JB + jx;
    float cx = 0.f;
#pragma unroll
    for (int e = 0; e < 8; ++e) cx += ex[e] * arena[(sp * 8 + e) * 260 + gj];
    cx *= inv;
    cx += __shfl_xor(cx, 1);
    cx += __shfl_xor(cx, 2);
    cx += __shfl_xor(cx, 4);
    if (sp == 0)
      __hip_atomic_store(ctxT + b * HID + gj,
                         (((u64)__float_as_uint(cx)) << 32) | 1ull,
                         __ATOMIC_RELAXED, __HIP_MEMORY_SCOPE_AGENT);
  }
  __syncthreads();   // all xs/was/Ls reads done -> smem reusable as lds_w

  // ---- W staging (global fp32 -> LDS fp16 k-pair half2), 16 b128/thread ----
#define STAGE_W16(SRC)                                                       \
  _Pragma("unroll")                                                          \
  for (int i = 0; i < 16; ++i) {                                             \
    const int idx = i * 256 + tid;                                           \
    const int kp = idx >> 5, c4 = idx & 31;                                  \
    const int gc = (c4 >> 3) * HID + q * JB + (c4 & 7) * 4;                  \
    const float4 a  = *(const float4*)((SRC) + (size_t)(2 * kp) * G4 + gc);  \
    const float4 b2 = *(const float4*)((SRC) + (size_t)(2 * kp + 1) * G4 + gc);\
    *(uint4*)&lds_w[kp * 128 + c4 * 4] =                                     \
        make_uint4(pk2(a.x, b2.x), pk2(a.y, b2.y),                           \
                   pk2(a.z, b2.z), pk2(a.w, b2.w));                          \
  }

  // MAC vs fp16 W tile: acc.e = gate g, hidden jq*4+e, k = kq*32..+31.
#define MACW(H2SRC, ACC)                                                     \
  _Pragma("unroll")                                                          \
  for (int kpl = 0; kpl < 16; ++kpl) {                                       \
    const uint4 wq = *(const uint4*)&lds_w[(kq * 16 + kpl) * 128 + cq4 * 4]; \
    const u32 h2 = (H2SRC)[kpl];                                             \
    ACC.x = dot2_(wq.x, h2, ACC.x);                                          \
    ACC.y = dot2_(wq.y, h2, ACC.y);                                          \
    ACC.z = dot2_(wq.z, h2, ACC.z);                                          \
    ACC.w = dot2_(wq.w, h2, ACC.w);                                          \
  }

  // =================== phase B: Wi tile, ctx poll, Gc ===================
  STAGE_W16(Wi)
  {  // poll full ctx (tag=1) -> cs (fp32)
    const u64* pp = ctxT + b * HID + tid;
    u64 pk;
    do {
      pk = __hip_atomic_load(pp, __ATOMIC_RELAXED, __HIP_MEMORY_SCOPE_AGENT);
    } while ((u32)pk != 1u);
    cs[tid] = __uint_as_float((u32)(pk >> 32));
  }
  __syncthreads();

  {
    u32 ch2[16];
    const float2* cp = (const float2*)&cs[kq * 32];
#pragma unroll
    for (int i = 0; i < 16; ++i) ch2[i] = pk2(cp[i].x, cp[i].y);
    float4 ac = {0.f, 0.f, 0.f, 0.f};
    MACW(ch2, ac)
    *(float4*)&gred[0][kq][cq4 * 4] = ac;
  }
  __syncthreads();

  float4 gcr = {0.f, 0.f, 0.f, 0.f};          // Gc + bias (reducer registers)
  float  cst = 0.f;                           // c state  (reducer registers)
  if (tid < 32) {                             // reducer for hidden j = tid
    const int qj = q * JB + tid;
#pragma unroll
    for (int k2 = 0; k2 < 8; ++k2) {
      const float* gp = &gred[0][k2][tid];
      gcr.x += gp[0]; gcr.y += gp[32]; gcr.z += gp[64]; gcr.w += gp[96];
    }
    gcr.x += bias[qj];           gcr.y += bias[HID + qj];
    gcr.z += bias[2 * HID + qj]; gcr.w += bias[3 * HID + qj];
    // step 0 (h=0): gates = Gc; publish tag 1 (overlaps Wh staging below)
    const float ig = sigmoid_f(gcr.x);
    const float g2 = tanh_f(gcr.z), og = sigmoid_f(gcr.w);
    cst = ig * g2;
    const float hv = og * tanh_f(cst);
    const float hp_ = __shfl_xor(hv, 1);      // lanes 0..31 all active
    if ((tid & 1) == 0) {
      const u32 d = pk2(hv, hp_);             // lo = h_2i, hi = h_2i+1
      __hip_atomic_store(tht2 + (size_t)BSZ * 128 + b * 128 + q * 16 + (tid >> 1),
                         (((u64)d) << 32) | 1ull,
                         __ATOMIC_RELAXED, __HIP_MEMORY_SCOPE_AGENT);
    }
  }
  STAGE_W16(Wh)    // overwrites Wi tile; gred (separate buffer) still readable
  __syncthreads();

  // =================== phase C: recurrent steps 1..63 ===================
  for (int t = 1; t < NSTEP; ++t) {
    const int rb = t & 1;
    {
      const u64* pp = tht2 + (size_t)rb * BSZ * 128 + b * 128 + (tid >> 1);
      u64 pk;
      do {
        pk = __hip_atomic_load(pp, __ATOMIC_RELAXED, __HIP_MEMORY_SCOPE_AGENT);
      } while ((u32)pk != (u32)t);
      hs2[tid >> 1] = (u32)(pk >> 32);        // lane pairs write same value
    }
    // hs2 RAW is half-wave-local: word w in [kq*16,kq*16+16) is staged by
    // tids 2w,2w+1 in [kq*32, kq*32+32) = the reader's own half-wave.
    float4 a2 = {0.f, 0.f, 0.f, 0.f};
    {
      const u32* hp = &hs2[kq * 16];
      u32 hh[16];
#pragma unroll
      for (int i4 = 0; i4 < 4; ++i4) {
        const uint4 hq = *(const uint4*)&hp[i4 * 4];
        hh[i4 * 4 + 0] = hq.x; hh[i4 * 4 + 1] = hq.y;
        hh[i4 * 4 + 2] = hq.z; hh[i4 * 4 + 3] = hq.w;
      }
      MACW(hh, a2)
    }
    *(float4*)&gred[rb][kq][cq4 * 4] = a2;
    __syncthreads();

    if (tid < 32) {   // reducer for hidden j = tid: 8 kq partials + Gc
      float4 s = gcr;
#pragma unroll
      for (int k2 = 0; k2 < 8; ++k2) {
        const float* gp = &gred[rb][k2][tid];
        s.x += gp[0]; s.y += gp[32]; s.z += gp[64]; s.w += gp[96];
      }
      const float ig = sigmoid_f(s.x), fg = sigmoid_f(s.y);
      const float g2 = tanh_f(s.z),    og = sigmoid_f(s.w);
      cst = fg * cst + ig * g2;
      const float hv = og * tanh_f(cst);
      const float hp_ = __shfl_xor(hv, 1);
      if ((tid & 1) == 0) {
        const u32 d = pk2(hv, hp_);
        __hip_atomic_store(tht2 + (size_t)((t + 1) & 1) * BSZ * 128
                               + b * 128 + q * 16 + (tid >> 1),
                           (((u64)d) << 32) | (u64)(u32)(t + 1),
                           __ATOMIC_RELAXED, __HIP_MEMORY_SCOPE_AGENT);
      }
    }
    // parity safety (R6 proof): tag t+1 overwrites tag t-1 words only after
    // ALL blocks published t, which requires all reads of t-1 completed.
  }

  // =================== epilogue: out[b] = ht @ Wf + bf ===================
  if (q == 0) {
    const u64* pp = tht2 + /*parity 0*/ b * 128 + (tid >> 1);
    u64 pk;
    do {
      pk = __hip_atomic_load(pp, __ATOMIC_RELAXED, __HIP_MEMORY_SCOPE_AGENT);
    } while ((u32)pk != (u32)NSTEP);
    const h2v hh = __builtin_bit_cast(h2v, (u32)(pk >> 32));
    const float hval = (tid & 1) ? (float)hh[1] : (float)hh[0];
    float prod = hval * Wf[tid];
#pragma unroll
    for (int mk = 1; mk < 64; mk <<= 1) prod += __shfl_xor(prod, mk);
    if (lane == 0) red[wv] = prod;
    __syncthreads();
    if (tid == 0) out[b] = red[0] + red[1] + red[2] + red[3] + bf[0];
  }
#undef MACW
#undef STAGE_W16
}

// ---------------------------------------------------------------------------
extern "C" void kernel_launch(void* const* d_in, const int* in_sizes, int n_in,
                              void* d_out, int out_size, void* d_ws, size_t ws_size,
                              hipStream_t stream)
{
  const float* x  = (const float*)d_in[0];
  const float* Wa = (const float*)d_in[1];
  // d_in[2] = ba: unused — constant along softmax axis, cancels exactly
  const float* Wi = (const float*)d_in[3];
  const float* Wh = (const float*)d_in[4];
  const float* bi = (const float*)d_in[5];
  const float* Wf = (const float*)d_in[6];
  const float* bf = (const float*)d_in[7];
  float* out = (float*)d_out;

  // ws: [0,64KB) tagged packed ht (2 parity bufs x 32 b x 128 words);
  //     [64KB,128KB) tagged ctx (32 b x 256 words)
  u64* tht2 = (u64*)d_ws;
  u64* ctxT = (u64*)((char*)d_ws + (size_t)2 * BSZ * 128 * sizeof(u64));

  hipLaunchKernelGGL(k_fused, dim3(BSZ * QB), dim3(256), 0, stream,
                     x, Wa, Wi, Wh, bi, Wf, bf, tht2, ctxT, out);
}